// Round 4
// baseline (814.827 us; speedup 1.0000x reference)
//
#include <hip/hip_runtime.h>
#include <math.h>

// Problem constants
#define BATCH 128
#define CIN   3
#define DIN   16
#define HWIN  64
#define COUT  24
#define DOUT  14   // 16 - 3 + 1
#define HOUT  62   // 64 - 3 + 1
#define WOUT  62
#define HW2   (HWIN * HWIN)
#define RS    68   // padded LDS row stride (floats)

// x:    [128][3][16][64][64]  fp32
// w:    [24][3][3][3][3]      fp32  (co, cin, kd, kh, kw)
// bias: [24]
// out:  [128][24][62][62]     fp32 softmax over channel dim
//
// v4: wave-uniform output channels -> weights live in SGPRs via s_load
// (v3 spilled 81 per-lane weight VGPRs to scratch: WRITE_SIZE 50->313MB).
// Block = 256 thr = 4 waves, one (b,ho) row; lane = pixel wo (62/64 used);
// wave owns channels 6*wave .. 6*wave+5. Rolling depth accumulators
// acc[j][0..2] (dz=d-2, d-1, d): each staged plane is LDS-read ONCE
// (27 ds_read_b32/lane) and feeds 486 SGPRxVGPR FMAs per wave.

template<bool K0, bool K1, bool K2>
__device__ __forceinline__ void do_plane(const float* __restrict__ sxp,
                                         const float* __restrict__ wb,
                                         int lane, float acc[6][3])
{
    // lane's full 3x3x3-cin window of this plane: 27 LDS reads, stride-1
    // across lanes (2-way bank alias = free).
    float xr[27];
    #pragma unroll
    for (int row = 0; row < 9; ++row) {
        xr[row * 3 + 0] = sxp[row * RS + lane + 0];
        xr[row * 3 + 1] = sxp[row * RS + lane + 1];
        xr[row * 3 + 2] = sxp[row * RS + lane + 2];
    }
    #pragma unroll
    for (int j = 0; j < 6; ++j) {
        #pragma unroll
        for (int cin = 0; cin < 3; ++cin) {
            // 27 contiguous weights (kd,kh,kw) at an SGPR base + const offset
            const float* wc = wb + j * 81 + cin * 27;
            #pragma unroll
            for (int kh = 0; kh < 3; ++kh) {
                #pragma unroll
                for (int kw = 0; kw < 3; ++kw) {
                    const float xv = xr[(cin * 3 + kh) * 3 + kw];
                    if (K0) acc[j][2] = fmaf(wc[0 * 9 + kh * 3 + kw], xv, acc[j][2]); // dz=d
                    if (K1) acc[j][1] = fmaf(wc[1 * 9 + kh * 3 + kw], xv, acc[j][1]); // dz=d-1
                    if (K2) acc[j][0] = fmaf(wc[2 * 9 + kh * 3 + kw], xv, acc[j][0]); // dz=d-2
                }
            }
        }
    }
}

__global__ __launch_bounds__(256, 4) void conv_min_softmax_v4(
    const float* __restrict__ x,
    const float* __restrict__ w,
    const float* __restrict__ bias,
    float* __restrict__ out)
{
    __shared__ __align__(16) float sx[9 * RS];     // one depth plane [cin*3+kh][col]
    __shared__ float sm[COUT][RS];                 // channel mins for softmax

    const int tid  = threadIdx.x;
    const int bid  = blockIdx.x;         // 0 .. 128*62-1
    const int ho   = bid % HOUT;
    const int b    = bid / HOUT;
    const int lane = tid & 63;           // pixel wo (62,63 compute junk)
    const int wave = __builtin_amdgcn_readfirstlane(tid >> 6);   // 0..3, SGPR

    const float* xb = x + (size_t)b * (CIN * DIN * HW2);
    const float* wb = w + wave * 6 * 81;           // SGPR base -> s_load weights

    // ---- staging map: 9 rows x 64 cols = 576 elems, 256 threads ----
    // e0 = tid (rows 0..3), e1 = tid+256 (rows 4..7), e2 = tid+512 (row 8, tid<64)
    const int row0 = tid >> 6;           // 0..3
    const int row1 = row0 + 4;           // 4..7
    const int c0 = row0 / 3, h0 = row0 % 3;
    const int c1 = row1 / 3, h1 = row1 % 3;
    const size_t base0 = (size_t)c0 * DIN * HW2 + (ho + h0) * HWIN + lane;
    const size_t base1 = (size_t)c1 * DIN * HW2 + (ho + h1) * HWIN + lane;
    const size_t base2 = (size_t)2  * DIN * HW2 + (ho + 2)  * HWIN + lane; // row 8

    float acc[6][3], m[6];
    #pragma unroll
    for (int j = 0; j < 6; ++j) {
        acc[j][0] = 0.f; acc[j][1] = 0.f; acc[j][2] = 0.f; m[j] = 1e30f;
    }

    // prefetch plane 0
    float g0 = xb[base0];
    float g1 = xb[base1];
    float g2 = (tid < 64) ? xb[base2] : 0.f;
    float n0, n1, n2;

#define STAGE(D)                                                           \
    sx[row0 * RS + lane] = g0;                                             \
    sx[row1 * RS + lane] = g1;                                             \
    if (tid < 64) sx[8 * RS + lane] = g2;                                  \
    if ((D) < DIN - 1) {                                                   \
        n0 = xb[base0 + ((D) + 1) * HW2];                                  \
        n1 = xb[base1 + ((D) + 1) * HW2];                                  \
        if (tid < 64) n2 = xb[base2 + ((D) + 1) * HW2];                    \
    }                                                                      \
    __syncthreads();

#define SHIFT()                                                            \
    _Pragma("unroll")                                                      \
    for (int j = 0; j < 6; ++j) {                                          \
        acc[j][0] = acc[j][1]; acc[j][1] = acc[j][2]; acc[j][2] = 0.f;     \
    }                                                                      \
    g0 = n0; g1 = n1; g2 = n2;

#define TAKE_MIN()                                                         \
    _Pragma("unroll")                                                      \
    for (int j = 0; j < 6; ++j) m[j] = fminf(m[j], acc[j][0]);

    // d = 0: only kd=0 (starts dz=0)
    STAGE(0)
    do_plane<true, false, false>(sx, wb, lane, acc);
    SHIFT()
    __syncthreads();

    // d = 1: kd=0,1
    STAGE(1)
    do_plane<true, true, false>(sx, wb, lane, acc);
    SHIFT()
    __syncthreads();

    // d = 2..13: all taps; finalize dz = d-2
    #pragma unroll 1
    for (int d = 2; d <= 13; ++d) {
        STAGE(d)
        do_plane<true, true, true>(sx, wb, lane, acc);
        TAKE_MIN()
        SHIFT()
        __syncthreads();
    }

    // d = 14: kd=1,2; finalize dz=12
    STAGE(14)
    do_plane<false, true, true>(sx, wb, lane, acc);
    TAKE_MIN()
    SHIFT()
    __syncthreads();

    // d = 15: kd=2 only; finalize dz=13
    STAGE(15)
    do_plane<false, false, true>(sx, wb, lane, acc);
    TAKE_MIN()

#undef STAGE
#undef SHIFT
#undef TAKE_MIN

    // ---- epilogue: bias, per-pixel softmax over the 24 channels ----
    #pragma unroll
    for (int j = 0; j < 6; ++j) {
        const int c = wave * 6 + j;
        sm[c][lane] = m[j] + bias[c];    // bias[c]: uniform addr -> s_load
    }
    __syncthreads();

    if (tid < WOUT) {
        const int p = tid;
        float mx = -1e30f;
        #pragma unroll
        for (int c = 0; c < COUT; ++c) mx = fmaxf(mx, sm[c][p]);
        float e[COUT];
        float ssum = 0.f;
        #pragma unroll
        for (int c = 0; c < COUT; ++c) { e[c] = __expf(sm[c][p] - mx); ssum += e[c]; }
        const float inv = 1.f / ssum;
        float* ob = out + (size_t)b * COUT * (HOUT * WOUT) + ho * WOUT + p;
        #pragma unroll
        for (int c = 0; c < COUT; ++c) ob[(size_t)c * (HOUT * WOUT)] = e[c] * inv;
    }
}

extern "C" void kernel_launch(void* const* d_in, const int* in_sizes, int n_in,
                              void* d_out, int out_size, void* d_ws, size_t ws_size,
                              hipStream_t stream) {
    const float* x    = (const float*)d_in[0];
    const float* w    = (const float*)d_in[1];
    const float* bias = (const float*)d_in[2];
    float* out = (float*)d_out;

    const int blocks = BATCH * HOUT;     // 7936
    conv_min_softmax_v4<<<blocks, 256, 0, stream>>>(x, w, bias, out);
}

// Round 5
// 614.407 us; speedup vs baseline: 1.3262x; 1.3262x over previous
//
#include <hip/hip_runtime.h>
#include <math.h>

// Problem constants
#define BATCH 128
#define CIN   3
#define DIN   16
#define HWIN  64
#define COUT  24
#define DOUT  14   // 16 - 3 + 1
#define HOUT  62   // 64 - 3 + 1
#define WOUT  62
#define HW2   (HWIN * HWIN)
#define RS    68   // padded LDS row stride for sx (keeps 16B align, allows +2 overread)

// x:    [128][3][16][64][64]  fp32
// w:    [24][3][3][3][3]      fp32  (co, cin, kd, kh, kw)
// bias: [24]
// out:  [128][24][62][62]     fp32 softmax over channel dim
//
// v5 = v2's proven layout (block = (b,ho) row; 192 thr = 24 co x 8 pixel
// strips; weights re-fetched from L1 per use -> no register hoarding)
// + rolling depth accumulators: each staged plane is LDS-read ONCE
// (9 rows/plane vs 27/dz in v2 -> 3x less LDS traffic, v2's binding pipe)
// + sm padded to 65 cols (kills v2's 3.2e7 epilogue bank-conflict cycles).

template<bool K0, bool K1, bool K2>
__device__ __forceinline__ void plane_fma(const float* __restrict__ sxp,
                                          const float* __restrict__ wco,
                                          int wg, float A[3][8])
{
    #pragma unroll
    for (int cin = 0; cin < 3; ++cin) {
        #pragma unroll
        for (int kh = 0; kh < 3; ++kh) {
            const float* rp = sxp + (cin * 3 + kh) * RS + wg * 8;
            float xr[10];
            const float4 q0 = *(const float4*)(rp);
            const float4 q1 = *(const float4*)(rp + 4);
            const float2 q2 = *(const float2*)(rp + 8);
            xr[0] = q0.x; xr[1] = q0.y; xr[2] = q0.z; xr[3] = q0.w;
            xr[4] = q1.x; xr[5] = q1.y; xr[6] = q1.z; xr[7] = q1.w;
            xr[8] = q2.x; xr[9] = q2.y;
            #pragma unroll
            for (int kw = 0; kw < 3; ++kw) {
                if (K0) {   // this plane is tap kd=0 of dz=d  -> A[2]
                    const float wv = wco[cin * 27 + 0 * 9 + kh * 3 + kw];
                    #pragma unroll
                    for (int i = 0; i < 8; ++i) A[2][i] = fmaf(wv, xr[i + kw], A[2][i]);
                }
                if (K1) {   // tap kd=1 of dz=d-1 -> A[1]
                    const float wv = wco[cin * 27 + 1 * 9 + kh * 3 + kw];
                    #pragma unroll
                    for (int i = 0; i < 8; ++i) A[1][i] = fmaf(wv, xr[i + kw], A[1][i]);
                }
                if (K2) {   // tap kd=2 of dz=d-2 -> A[0] (finalized after this plane)
                    const float wv = wco[cin * 27 + 2 * 9 + kh * 3 + kw];
                    #pragma unroll
                    for (int i = 0; i < 8; ++i) A[0][i] = fmaf(wv, xr[i + kw], A[0][i]);
                }
            }
        }
    }
}

__global__ __launch_bounds__(192, 3) void conv_min_softmax_v5(
    const float* __restrict__ x,
    const float* __restrict__ w,
    const float* __restrict__ bias,
    float* __restrict__ out)
{
    __shared__ __align__(16) float sx[9 * RS];   // one depth plane [cin*3+kh][col]
    __shared__ float sm[COUT][65];               // pad 65: (co+col)%32 -> conflict-free

    const int tid = threadIdx.x;
    const int bid = blockIdx.x;          // 0 .. 128*62-1
    const int ho  = bid % HOUT;
    const int b   = bid / HOUT;

    const int co = tid >> 3;             // 0..23  (this thread's output channel)
    const int wg = tid & 7;              // 0..7   (pixels wo = wg*8 .. wg*8+7)

    const float* xb  = x + (size_t)b * (CIN * DIN * HW2);
    const float* wco = w + co * 81;      // per-lane; L1-cached re-fetch per use (v2-proven)

    // staging map: thread loads one element per cin (3 rows of the plane)
    const int r  = tid >> 6;             // 0..2 input row within plane
    const int wc = tid & 63;             // 0..63 col

    float A[3][8], m[8];
    #pragma unroll
    for (int i = 0; i < 8; ++i) { A[0][i] = 0.f; A[1][i] = 0.f; A[2][i] = 0.f; m[i] = 1e30f; }

    // prefetch plane 0 into g*, software-pipelined with compute
    float g0 = xb[(0 * DIN + 0) * HW2 + (ho + r) * HWIN + wc];
    float g1 = xb[(1 * DIN + 0) * HW2 + (ho + r) * HWIN + wc];
    float g2 = xb[(2 * DIN + 0) * HW2 + (ho + r) * HWIN + wc];
    float n0, n1, n2;

#define STAGE(D)                                                           \
    sx[(0 * 3 + r) * RS + wc] = g0;                                        \
    sx[(1 * 3 + r) * RS + wc] = g1;                                        \
    sx[(2 * 3 + r) * RS + wc] = g2;                                        \
    if ((D) < DIN - 1) {                                                   \
        n0 = xb[(0 * DIN + (D) + 1) * HW2 + (ho + r) * HWIN + wc];         \
        n1 = xb[(1 * DIN + (D) + 1) * HW2 + (ho + r) * HWIN + wc];         \
        n2 = xb[(2 * DIN + (D) + 1) * HW2 + (ho + r) * HWIN + wc];         \
    }                                                                      \
    __syncthreads();

#define SHIFT()                                                            \
    _Pragma("unroll")                                                      \
    for (int i = 0; i < 8; ++i) { A[0][i] = A[1][i]; A[1][i] = A[2][i]; A[2][i] = 0.f; } \
    g0 = n0; g1 = n1; g2 = n2;

#define TAKE_MIN()                                                         \
    _Pragma("unroll")                                                      \
    for (int i = 0; i < 8; ++i) m[i] = fminf(m[i], A[0][i]);

    // d = 0: plane feeds only dz=0 (kd=0)
    STAGE(0)
    plane_fma<true, false, false>(sx, wco, wg, A);
    SHIFT()
    __syncthreads();

    // d = 1: kd=0 of dz=1, kd=1 of dz=0
    STAGE(1)
    plane_fma<true, true, false>(sx, wco, wg, A);
    SHIFT()
    __syncthreads();

    // d = 2..13: all three taps; dz=d-2 finalized each step
    #pragma unroll 1
    for (int d = 2; d <= 13; ++d) {
        STAGE(d)
        plane_fma<true, true, true>(sx, wco, wg, A);
        TAKE_MIN()
        SHIFT()
        __syncthreads();
    }

    // d = 14: kd=1,2; finalizes dz=12
    STAGE(14)
    plane_fma<false, true, true>(sx, wco, wg, A);
    TAKE_MIN()
    SHIFT()
    __syncthreads();

    // d = 15: kd=2 only; finalizes dz=13
    STAGE(15)
    plane_fma<false, false, true>(sx, wco, wg, A);
    TAKE_MIN()

#undef STAGE
#undef SHIFT
#undef TAKE_MIN

    // ---- epilogue: bias, then per-pixel softmax across the 24 channels ----
    const float bco = bias[co];
    #pragma unroll
    for (int i = 0; i < 8; ++i) sm[co][wg * 8 + i] = m[i] + bco;  // cols 62..64 junk/unused
    __syncthreads();

    if (tid < WOUT) {
        const int p = tid;
        float mx = -1e30f;
        #pragma unroll
        for (int c = 0; c < COUT; ++c) mx = fmaxf(mx, sm[c][p]);
        float e[COUT];
        float ssum = 0.f;
        #pragma unroll
        for (int c = 0; c < COUT; ++c) { e[c] = __expf(sm[c][p] - mx); ssum += e[c]; }
        const float inv = 1.f / ssum;
        float* ob = out + (size_t)b * COUT * (HOUT * WOUT) + ho * WOUT + p;
        #pragma unroll
        for (int c = 0; c < COUT; ++c) ob[(size_t)c * (HOUT * WOUT)] = e[c] * inv;
    }
}

extern "C" void kernel_launch(void* const* d_in, const int* in_sizes, int n_in,
                              void* d_out, int out_size, void* d_ws, size_t ws_size,
                              hipStream_t stream) {
    const float* x    = (const float*)d_in[0];
    const float* w    = (const float*)d_in[1];
    const float* bias = (const float*)d_in[2];
    float* out = (float*)d_out;

    const int blocks = BATCH * HOUT;     // 7936
    conv_min_softmax_v5<<<blocks, 192, 0, stream>>>(x, w, bias, out);
}